// Round 2
// baseline (614.810 us; speedup 1.0000x reference)
//
#include <hip/hip_runtime.h>
#include <hip/hip_bf16.h>
#include <math.h>

// Problem constants (AttnBlock: B=16, C=256, H=W=64, heads=4, dim_head=32)
#define BATCH 16
#define CH 256
#define NPOS 4096        // 64*64 spatial positions
#define INNER 128        // heads * dim_head
#define HEADS 4
#define DH 32
#define QKV_ROWS 384     // 3 * INNER

typedef __hip_bfloat16 bf16;

__device__ __forceinline__ float b2f(bf16 v) { return __bfloat162float(v); }
__device__ __forceinline__ bf16 f2b(float v) { return __float2bfloat16(v); }
__device__ __forceinline__ float ld(const bf16* p)  { return __bfloat162float(*p); }
__device__ __forceinline__ float ld(const float* p) { return *p; }

// ---------------------------------------------------------------------------
// Kernel 1: per-position LayerNorm stats over channels (mu, rsigma)
// thread per (b, n); reads x[b, c, n] stride-N -> coalesced across lanes
// ---------------------------------------------------------------------------
__global__ void ln_stats_kernel(const float* __restrict__ x,
                                float* __restrict__ mu, float* __restrict__ rsig) {
    int gid = blockIdx.x * blockDim.x + threadIdx.x;   // 65536 = B*N
    int b = gid >> 12;
    int n = gid & (NPOS - 1);
    const float* px = x + (size_t)b * CH * NPOS + n;
    float s = 0.f, sq = 0.f;
    for (int c = 0; c < CH; ++c) {
        float v = px[(size_t)c * NPOS];
        s += v; sq += v * v;
    }
    float m   = s * (1.f / CH);
    float var = sq * (1.f / CH) - m * m;
    mu[gid]   = m;
    rsig[gid] = rsqrtf(var + 1e-5f);
}

// ---------------------------------------------------------------------------
// Kernel 2/7: tiled GEMM  C[b] = A (MxK, fp32) * B[b] (KxN) (+bias)
// If mu != null, B elements are LayerNorm'ed on load: (v - mu[n]) * rsig[n]
// 64x64 tile, BK=32, 256 threads, 4x4 microtile, fp32 accumulate, bf16 out.
// ---------------------------------------------------------------------------
template <typename TB>
__global__ void gemm_kernel(const float* __restrict__ A, const TB* __restrict__ Bbase,
                            bf16* __restrict__ Cbase, int M, int K,
                            const float* __restrict__ mu_all, const float* __restrict__ rsig_all,
                            const float* __restrict__ bias) {
    __shared__ float As[32][68];   // [k][m], padded
    __shared__ float Bs[32][68];   // [k][n], padded

    int b  = blockIdx.z;
    int m0 = blockIdx.y * 64;
    int n0 = blockIdx.x * 64;
    const TB* B = Bbase + (size_t)b * K * NPOS;
    bf16*     C = Cbase + (size_t)b * M * NPOS;
    const float* mu   = mu_all   ? mu_all   + (size_t)b * NPOS : nullptr;
    const float* rsig = rsig_all ? rsig_all + (size_t)b * NPOS : nullptr;

    int tid  = threadIdx.x;
    int mrow = tid >> 4;        // 0..15
    int ncol = tid & 15;        // 0..15

    float acc[4][4] = {};

    for (int k0 = 0; k0 < K; k0 += 32) {
        // stage A tile: 64 rows x 32 k (A is row-major MxK, contiguous in k)
        for (int i = tid; i < 64 * 32; i += 256) {
            int m = i >> 5, k = i & 31;
            As[k][m] = A[(size_t)(m0 + m) * K + (k0 + k)];
        }
        // stage B tile: 32 k x 64 n (contiguous in n), optional fused LN
        for (int i = tid; i < 32 * 64; i += 256) {
            int k = i >> 6, n = i & 63;
            float v = ld(&B[(size_t)(k0 + k) * NPOS + (n0 + n)]);
            if (mu) v = (v - mu[n0 + n]) * rsig[n0 + n];
            Bs[k][n] = v;
        }
        __syncthreads();
        #pragma unroll
        for (int kk = 0; kk < 32; ++kk) {
            float4 av = *(const float4*)&As[kk][mrow * 4];
            float4 bv = *(const float4*)&Bs[kk][ncol * 4];
            float a[4] = {av.x, av.y, av.z, av.w};
            float bb[4] = {bv.x, bv.y, bv.z, bv.w};
            #pragma unroll
            for (int i = 0; i < 4; ++i)
                #pragma unroll
                for (int j = 0; j < 4; ++j)
                    acc[i][j] += a[i] * bb[j];
        }
        __syncthreads();
    }

    #pragma unroll
    for (int i = 0; i < 4; ++i) {
        int m = m0 + mrow * 4 + i;
        float bv = bias ? bias[m] : 0.f;
        #pragma unroll
        for (int j = 0; j < 4; ++j) {
            int n = n0 + ncol * 4 + j;
            C[(size_t)m * NPOS + n] = f2b(acc[i][j] + bv);
        }
    }
}

// ---------------------------------------------------------------------------
// Kernel 3: q softmax over dim_head (32 channels per (b,h,n)); folds 1/sqrt(32)
// thread per (b,h,n); in-place on qkv rows [0,128)
// ---------------------------------------------------------------------------
__global__ void q_softmax_kernel(bf16* __restrict__ qkv) {
    int gid = blockIdx.x * blockDim.x + threadIdx.x;   // B*HEADS*N = 262144
    int n  = gid & (NPOS - 1);
    int bh = gid >> 12;
    int b = bh >> 2, h = bh & 3;
    bf16* p = qkv + (size_t)b * QKV_ROWS * NPOS + (size_t)(h * DH) * NPOS + n;
    float v[32];
    float mx = -1e30f;
    #pragma unroll
    for (int d = 0; d < 32; ++d) { v[d] = b2f(p[(size_t)d * NPOS]); mx = fmaxf(mx, v[d]); }
    float s = 0.f;
    #pragma unroll
    for (int d = 0; d < 32; ++d) { v[d] = __expf(v[d] - mx); s += v[d]; }
    float inv = 0.17677669529663688f / s;   // (1/sqrt(32)) / sum
    #pragma unroll
    for (int d = 0; d < 32; ++d) p[(size_t)d * NPOS] = f2b(v[d] * inv);
}

// ---------------------------------------------------------------------------
// Kernel 4: k softmax over N (4096) per (b, k-channel); block per row
// in-place on qkv rows [128,256)
// ---------------------------------------------------------------------------
__global__ void k_softmax_kernel(bf16* __restrict__ qkv) {
    int b = blockIdx.x >> 7;        // 2048 blocks = 16 * 128
    int r = blockIdx.x & 127;
    bf16* p = qkv + (size_t)b * QKV_ROWS * NPOS + (size_t)(INNER + r) * NPOS;
    int tid = threadIdx.x;
    __shared__ float red[256];

    float v[16];
    float mx = -1e30f;
    #pragma unroll
    for (int i = 0; i < 16; ++i) { v[i] = b2f(p[tid + i * 256]); mx = fmaxf(mx, v[i]); }
    red[tid] = mx; __syncthreads();
    for (int off = 128; off > 0; off >>= 1) {
        if (tid < off) red[tid] = fmaxf(red[tid], red[tid + off]);
        __syncthreads();
    }
    mx = red[0]; __syncthreads();

    float s = 0.f;
    #pragma unroll
    for (int i = 0; i < 16; ++i) { v[i] = __expf(v[i] - mx); s += v[i]; }
    red[tid] = s; __syncthreads();
    for (int off = 128; off > 0; off >>= 1) {
        if (tid < off) red[tid] += red[tid + off];
        __syncthreads();
    }
    float inv = 1.f / red[0];
    #pragma unroll
    for (int i = 0; i < 16; ++i) p[tid + i * 256] = f2b(v[i] * inv);
}

// ---------------------------------------------------------------------------
// Kernel 5: context[b,h,d,e] = (1/N) * sum_n k[d,n] * v[e,n]
// block per (b,h); folds the v/N scaling
// ---------------------------------------------------------------------------
__global__ void context_kernel(const bf16* __restrict__ qkv, float* __restrict__ ctx) {
    int b = blockIdx.x >> 2, h = blockIdx.x & 3;
    const bf16* kp = qkv + (size_t)b * QKV_ROWS * NPOS + (size_t)(INNER     + h * DH) * NPOS;
    const bf16* vp = qkv + (size_t)b * QKV_ROWS * NPOS + (size_t)(2 * INNER + h * DH) * NPOS;
    __shared__ float ks[32][129];
    __shared__ float vs[32][129];
    int tid = threadIdx.x;
    int e  = tid & 31;
    int dg = tid >> 5;   // 0..7
    float acc[4] = {0.f, 0.f, 0.f, 0.f};

    for (int nc = 0; nc < NPOS; nc += 128) {
        for (int i = tid; i < 32 * 128; i += 256) {
            int d = i >> 7, nn = i & 127;
            ks[d][nn] = b2f(kp[(size_t)d * NPOS + nc + nn]);
            vs[d][nn] = b2f(vp[(size_t)d * NPOS + nc + nn]);
        }
        __syncthreads();
        for (int nn = 0; nn < 128; ++nn) {
            float vv = vs[e][nn];
            #pragma unroll
            for (int j = 0; j < 4; ++j) acc[j] += ks[dg * 4 + j][nn] * vv;
        }
        __syncthreads();
    }
    const float scale = 1.f / NPOS;
    #pragma unroll
    for (int j = 0; j < 4; ++j) {
        int d = dg * 4 + j;
        ctx[((size_t)blockIdx.x * 32 + d) * 32 + e] = acc[j] * scale;
    }
}

// ---------------------------------------------------------------------------
// Kernel 6: attn[b, h*32+e, n] = sum_d ctx[d,e] * q[b, h*32+d, n]
// block per (b, h, 256-column tile); thread = column
// ---------------------------------------------------------------------------
__global__ void attn_out_kernel(const bf16* __restrict__ qkv, const float* __restrict__ ctx,
                                bf16* __restrict__ attn) {
    int n0 = blockIdx.x * 256;
    int h = blockIdx.y, b = blockIdx.z;
    const bf16* qp = qkv  + (size_t)b * QKV_ROWS * NPOS + (size_t)(h * DH) * NPOS;
    bf16*       op = attn + (size_t)b * INNER    * NPOS + (size_t)(h * DH) * NPOS;
    __shared__ float cs[32][32];
    __shared__ float qs[32][257];
    int tid = threadIdx.x;
    int bh = b * 4 + h;
    for (int i = tid; i < 1024; i += 256) cs[i >> 5][i & 31] = ctx[(size_t)bh * 1024 + i];
    for (int i = tid; i < 32 * 256; i += 256) {
        int d = i >> 8, j = i & 255;
        qs[d][j] = b2f(qp[(size_t)d * NPOS + n0 + j]);
    }
    __syncthreads();
    #pragma unroll 4
    for (int e = 0; e < 32; ++e) {
        float s = 0.f;
        #pragma unroll
        for (int d = 0; d < 32; ++d) s += cs[d][e] * qs[d][tid];
        op[(size_t)e * NPOS + n0 + tid] = f2b(s);
    }
}

// ---------------------------------------------------------------------------
// Kernel 7 uses gemm_kernel<bf16> (Wout @ attn + bout) -> y (bf16)
// ---------------------------------------------------------------------------

// ---------------------------------------------------------------------------
// Kernel 8: final LN over channels + residual; thread per (b,n); fp32 out
// ---------------------------------------------------------------------------
__global__ void final_ln_kernel(const bf16* __restrict__ y, const float* __restrict__ x,
                                float* __restrict__ out) {
    int gid = blockIdx.x * blockDim.x + threadIdx.x;
    int b = gid >> 12;
    int n = gid & (NPOS - 1);
    size_t base = (size_t)b * CH * NPOS + n;
    float s = 0.f, sq = 0.f;
    for (int c = 0; c < CH; ++c) {
        float v = b2f(y[base + (size_t)c * NPOS]);
        s += v; sq += v * v;
    }
    float m   = s * (1.f / CH);
    float var = sq * (1.f / CH) - m * m;
    float rs  = rsqrtf(var + 1e-5f);
    for (int c = 0; c < CH; ++c) {
        size_t idx = base + (size_t)c * NPOS;
        float v = (b2f(y[idx]) - m) * rs + x[idx];
        out[idx] = v;
    }
}

// ---------------------------------------------------------------------------
extern "C" void kernel_launch(void* const* d_in, const int* in_sizes, int n_in,
                              void* d_out, int out_size, void* d_ws, size_t ws_size,
                              hipStream_t stream) {
    const float* x    = (const float*)d_in[0];   // [16,256,64,64] fp32
    const float* Wqkv = (const float*)d_in[1];   // [384,256] fp32
    const float* Wout = (const float*)d_in[2];   // [256,128] fp32
    const float* bout = (const float*)d_in[3];   // [256] fp32
    float* out = (float*)d_out;                  // [16,256,64,64] fp32

    // workspace layout (~68 MB total, intermediates in bf16)
    char* ws = (char*)d_ws;
    bf16*  qkv  = (bf16*)ws;                                   // 16*384*4096*2 = 50331648
    bf16*  attn = (bf16*)(ws + 50331648);                      // 16*128*4096*2 = 16777216
    float* mu   = (float*)(ws + 67108864);                     // 65536*4
    float* rsig = (float*)(ws + 67371008);                     // 65536*4
    float* ctx  = (float*)(ws + 67633152);                     // 64*32*32*4
    bf16*  y    = (bf16*)ws;  // overlay: qkv region is dead once attn is written

    // 1) LN stats over channels
    ln_stats_kernel<<<256, 256, 0, stream>>>(x, mu, rsig);
    // 2) qkv = Wqkv @ LN(x)   (LN fused into B-tile load)
    gemm_kernel<float><<<dim3(NPOS / 64, QKV_ROWS / 64, BATCH), 256, 0, stream>>>(
        Wqkv, x, qkv, QKV_ROWS, CH, mu, rsig, nullptr);
    // 3) q softmax over dim_head (folds 1/sqrt(32))
    q_softmax_kernel<<<1024, 256, 0, stream>>>(qkv);
    // 4) k softmax over N
    k_softmax_kernel<<<2048, 256, 0, stream>>>(qkv);
    // 5) context = k^T v / N
    context_kernel<<<64, 256, 0, stream>>>(qkv, ctx);
    // 6) attn = ctx^T @ q
    attn_out_kernel<<<dim3(NPOS / 256, HEADS, BATCH), 256, 0, stream>>>(qkv, ctx, attn);
    // 7) y = Wout @ attn + bout
    gemm_kernel<bf16><<<dim3(NPOS / 64, CH / 64, BATCH), 256, 0, stream>>>(
        Wout, attn, y, CH, INNER, nullptr, nullptr, bout);
    // 8) out = LN(y) + x  (+ residual), fp32 out
    final_ln_kernel<<<256, 256, 0, stream>>>(y, x, out);
}

// Round 3
// 246.422 us; speedup vs baseline: 2.4949x; 2.4949x over previous
//
#include <hip/hip_runtime.h>
#include <hip/hip_bf16.h>
#include <math.h>

// AttnBlock: B=16, C=256, H=W=64, heads=4, dim_head=32
#define BATCH 16
#define CH 256
#define NPOS 4096
#define INNER 128
#define HEADS 4
#define DH 32
#define QKV_ROWS 384

typedef __hip_bfloat16 bf16;
typedef short bf8v __attribute__((ext_vector_type(8)));    // 8 bf16 (4 VGPRs)
typedef float f32x4 __attribute__((ext_vector_type(4)));

__device__ __forceinline__ float b2f(bf16 v) { return __bfloat162float(v); }
__device__ __forceinline__ bf16 f2b(float v) { return __float2bfloat16(v); }
__device__ __forceinline__ float us2f(unsigned short u) {
    unsigned w = ((unsigned)u) << 16; float f; __builtin_memcpy(&f, &w, 4); return f;
}
__device__ __forceinline__ unsigned short f2us(float f) {
    bf16 h = __float2bfloat16(f); unsigned short u; __builtin_memcpy(&u, &h, 2); return u;
}
// async global->LDS, 16B per lane; LDS dest = wave-uniform base + lane*16
__device__ __forceinline__ void gload16(const void* g, void* l) {
    __builtin_amdgcn_global_load_lds(
        (__attribute__((address_space(1))) unsigned int*)(g),
        (__attribute__((address_space(3))) unsigned int*)(l), 16, 0, 0);
}

// ---------------------------------------------------------------------------
// K1: channel-LN + transpose: x[b][c][n] fp32 -> xnt[b][n][c] bf16 (8 batches)
// block per (32-n tile, b_local); LDS 32x257 f32
// ---------------------------------------------------------------------------
__global__ __launch_bounds__(256)
void norm_transpose_kernel(const float* __restrict__ x, bf16* __restrict__ xnt) {
    __shared__ float xs[32][257];
    __shared__ float red_s[8][32], red_q[8][32];
    __shared__ float mu_s[32], rs_s[32];
    int b = blockIdx.y;
    int n0 = blockIdx.x * 32;
    int tid = threadIdx.x;
    const float* xb = x + (size_t)b * CH * NPOS;
    for (int idx = tid; idx < 32 * 256; idx += 256) {
        int c = idx >> 5, n = idx & 31;
        xs[n][c] = xb[(size_t)c * NPOS + n0 + n];
    }
    __syncthreads();
    {
        int n = tid & 31, q = tid >> 5;  // 8 groups of 32 channels
        float s = 0.f, sq = 0.f;
        #pragma unroll
        for (int i = 0; i < 32; ++i) { float v = xs[n][q * 32 + i]; s += v; sq += v * v; }
        red_s[q][n] = s; red_q[q][n] = sq;
    }
    __syncthreads();
    if (tid < 32) {
        float s = 0.f, sq = 0.f;
        #pragma unroll
        for (int q = 0; q < 8; ++q) { s += red_s[q][tid]; sq += red_q[q][tid]; }
        float m = s * (1.f / 256.f);
        float var = sq * (1.f / 256.f) - m * m;
        mu_s[tid] = m; rs_s[tid] = rsqrtf(var + 1e-5f);
    }
    __syncthreads();
    bf16* ob = xnt + ((size_t)b * NPOS + n0) * CH;
    for (int idx = tid; idx < 32 * 256; idx += 256) {
        int n = idx >> 8, c = idx & 255;
        ob[(size_t)n * CH + c] = f2b((xs[n][c] - mu_s[n]) * rs_s[n]);
    }
}

// ---------------------------------------------------------------------------
// K2: Wqkv fp32 -> bf16 (row-major [384][256] unchanged)
// ---------------------------------------------------------------------------
__global__ __launch_bounds__(256)
void convert_wq_kernel(const float* __restrict__ Wqkv, bf16* __restrict__ wq) {
    int i = blockIdx.x * 256 + threadIdx.x;   // 98304 total
    wq[i] = f2b(Wqkv[i]);
}

// ---------------------------------------------------------------------------
// K3/K7: MFMA GEMM.  out[row][col] = sum_k Act[row][k] * W[col][k] (+bias[col])
// Act: [rows][lda] bf16 (batched, strideA); W: [cols][K] bf16 (strideB);
// C: [rows][ldc] bf16 (strideC). 128x128 tile, BK=32, 4 waves, 4x4 mfma/wave.
// 16x16x32 frags: A[m=lane&15][k=(lane>>4)*8+j], B[k=(lane>>4)*8+j][n=lane&15],
// D col=lane&15, row=(lane>>4)*4+reg   [per guide §3, m89/m91/m120]
// ---------------------------------------------------------------------------
__global__ __launch_bounds__(256)
void mfma_gemm_kernel(const bf16* __restrict__ A0, const bf16* __restrict__ B0,
                      bf16* __restrict__ C0, int K, int lda, int ldc,
                      long strideA, long strideB, long strideC,
                      const float* __restrict__ bias) {
    __shared__ bf16 Alds[128 * 32];   // [row][k], 64B rows, unpadded (global_load_lds)
    __shared__ bf16 Blds[128 * 32];
    const int bz = blockIdx.z;
    const bf16* A = A0 + (long)bz * strideA + (long)blockIdx.y * 128 * lda;
    const bf16* Bw = B0 + (long)bz * strideB + (long)blockIdx.x * 128 * K;
    bf16* C = C0 + (long)bz * strideC + (long)blockIdx.y * 128 * ldc + blockIdx.x * 128;

    const int tid = threadIdx.x;
    const int wave = tid >> 6, lane = tid & 63;
    const int wm = (wave >> 1) * 64, wn = (wave & 1) * 64;
    const int lrow = lane & 15, kq = lane >> 4;

    f32x4 zero = {0.f, 0.f, 0.f, 0.f};
    f32x4 acc[4][4];
    #pragma unroll
    for (int i = 0; i < 4; ++i)
        #pragma unroll
        for (int j = 0; j < 4; ++j) acc[i][j] = zero;

    for (int k0 = 0; k0 < K; k0 += 32) {
        // stage A,B tiles: chunk s = i*256+tid; row=s>>2, c=s&3 (16B chunks)
        {
            int s = tid, row = s >> 2, c = s & 3;
            int s2 = 256 + tid, row2 = s2 >> 2, c2 = s2 & 3;
            gload16(A + (long)row * lda + k0 + c * 8,  &Alds[(wave * 64) * 8]);
            gload16(A + (long)row2 * lda + k0 + c2 * 8, &Alds[(256 + wave * 64) * 8]);
            gload16(Bw + (long)row * K + k0 + c * 8,   &Blds[(wave * 64) * 8]);
            gload16(Bw + (long)row2 * K + k0 + c2 * 8,  &Blds[(256 + wave * 64) * 8]);
        }
        __syncthreads();
        bf8v af[4], bfr[4];
        #pragma unroll
        for (int t = 0; t < 4; ++t)
            af[t] = *(const bf8v*)&Alds[(wm + t * 16 + lrow) * 32 + kq * 8];
        #pragma unroll
        for (int t = 0; t < 4; ++t)
            bfr[t] = *(const bf8v*)&Blds[(wn + t * 16 + lrow) * 32 + kq * 8];
        #pragma unroll
        for (int mt = 0; mt < 4; ++mt)
            #pragma unroll
            for (int nt = 0; nt < 4; ++nt)
                acc[mt][nt] = __builtin_amdgcn_mfma_f32_16x16x32_bf16(
                    af[mt], bfr[nt], acc[mt][nt], 0, 0, 0);
        __syncthreads();
    }

    #pragma unroll
    for (int mt = 0; mt < 4; ++mt) {
        #pragma unroll
        for (int nt = 0; nt < 4; ++nt) {
            int col = wn + nt * 16 + lrow;
            float bv = bias ? bias[blockIdx.x * 128 + col] : 0.f;
            #pragma unroll
            for (int r = 0; r < 4; ++r) {
                int row = wm + mt * 16 + kq * 4 + r;
                C[(long)row * ldc + col] = f2b(acc[mt][nt][r] + bv);
            }
        }
    }
}

// ---------------------------------------------------------------------------
// K4: q softmax over dim_head, in-place on qkv_t cols [0,128)
// thread per (b,n,h): 32 contiguous bf16 (pure softmax; scales folded in Wmod)
// ---------------------------------------------------------------------------
__global__ __launch_bounds__(256)
void p_softmax_kernel(bf16* __restrict__ qkvt) {
    int gid = blockIdx.x * 256 + threadIdx.x;   // 262144
    int h = gid & 3, n = (gid >> 2) & (NPOS - 1), b = gid >> 14;
    bf16* p = qkvt + ((size_t)b * NPOS + n) * QKV_ROWS + h * DH;
    uint4* pv = (uint4*)p;
    uint4 u[4]; u[0] = pv[0]; u[1] = pv[1]; u[2] = pv[2]; u[3] = pv[3];
    unsigned* uw = (unsigned*)u;
    float v[32];
    #pragma unroll
    for (int i = 0; i < 16; ++i) {
        v[2 * i] = us2f((unsigned short)(uw[i] & 0xffffu));
        v[2 * i + 1] = us2f((unsigned short)(uw[i] >> 16));
    }
    float mx = v[0];
    #pragma unroll
    for (int i = 1; i < 32; ++i) mx = fmaxf(mx, v[i]);
    float s = 0.f;
    #pragma unroll
    for (int i = 0; i < 32; ++i) { v[i] = __expf(v[i] - mx); s += v[i]; }
    float inv = 1.f / s;
    #pragma unroll
    for (int i = 0; i < 16; ++i) {
        unsigned lo = f2us(v[2 * i] * inv), hi = f2us(v[2 * i + 1] * inv);
        uw[i] = lo | (hi << 16);
    }
    pv[0] = u[0]; pv[1] = u[1]; pv[2] = u[2]; pv[3] = u[3];
}

// ---------------------------------------------------------------------------
// K5: unnormalized context + sumexp partials.
// ctxu[(bh,sp)][d][e] = sum_n exp(k_raw[n,d]) * v_raw[n,e]; separt = sum exp.
// block per (sp,h,b): 1024 n; waves split n within each staged 128-tile.
// lane = (dg=lane>>3, eg=lane&7), 4x4 register tile.
// ---------------------------------------------------------------------------
__global__ __launch_bounds__(256)
void context_kernel(const bf16* __restrict__ qkvt, float* __restrict__ ctxu,
                    float* __restrict__ separt) {
    __shared__ float ks[128][36];
    __shared__ float vs[128][36];
    __shared__ float red_se[4][32];
    int sp = blockIdx.x, h = blockIdx.y, b = blockIdx.z;
    int tid = threadIdx.x;
    int wave = tid >> 6, lane = tid & 63;
    int eg = lane & 7, dg = lane >> 3;
    int sd = tid & 31, sq = (tid >> 5) & 3;
    const int koff = 128 + h * DH, voff = 256 + h * DH;
    size_t rowbase = ((size_t)b * NPOS + sp * 1024) * QKV_ROWS;

    float acc[4][4] = {};
    float se_loc = 0.f;

    for (int nc = 0; nc < 1024; nc += 128) {
        for (int t = tid; t < 1024; t += 256) {
            int n = t >> 3, dq = t & 7;
            const bf16* row = qkvt + rowbase + (size_t)(nc + n) * QKV_ROWS;
            ushort4 ku = *(const ushort4*)(row + koff + dq * 4);
            ushort4 vu = *(const ushort4*)(row + voff + dq * 4);
            f32x4 kf, vf;
            kf[0] = __expf(us2f(ku.x)); kf[1] = __expf(us2f(ku.y));
            kf[2] = __expf(us2f(ku.z)); kf[3] = __expf(us2f(ku.w));
            vf[0] = us2f(vu.x); vf[1] = us2f(vu.y); vf[2] = us2f(vu.z); vf[3] = us2f(vu.w);
            *(f32x4*)&ks[n][dq * 4] = kf;
            *(f32x4*)&vs[n][dq * 4] = vf;
        }
        __syncthreads();
        #pragma unroll 4
        for (int i = 0; i < 32; ++i) {
            int n = wave * 32 + i;
            f32x4 kv = *(const f32x4*)&ks[n][dg * 4];
            f32x4 vv = *(const f32x4*)&vs[n][eg * 4];
            #pragma unroll
            for (int j = 0; j < 4; ++j)
                #pragma unroll
                for (int i2 = 0; i2 < 4; ++i2)
                    acc[j][i2] += kv[j] * vv[i2];
        }
        if (tid < 128) {
            float s = 0.f;
            #pragma unroll 8
            for (int i = 0; i < 32; ++i) s += ks[sq * 32 + i][sd];
            se_loc += s;
        }
        __syncthreads();
    }

    if (tid < 128) red_se[sq][sd] = se_loc;
    float* red = &ks[0][0];   // reuse (4608 floats >= 4096)
    #pragma unroll
    for (int j = 0; j < 4; ++j)
        #pragma unroll
        for (int i = 0; i < 4; ++i)
            red[(wave * 64 + lane) * 16 + j * 4 + i] = acc[j][i];
    __syncthreads();
    size_t bhsp = ((size_t)(b * HEADS + h) * 4 + sp);
    for (int idx = tid; idx < 1024; idx += 256) {
        int d = idx >> 5, e = idx & 31;
        int l = (d >> 2) * 8 + (e >> 2);
        int slot = (d & 3) * 4 + (e & 3);
        float s = 0.f;
        #pragma unroll
        for (int w = 0; w < 4; ++w) s += red[(w * 64 + l) * 16 + slot];
        ctxu[bhsp * 1024 + idx] = s;
    }
    if (tid < 32) {
        float s = red_se[0][tid] + red_se[1][tid] + red_se[2][tid] + red_se[3][tid];
        separt[bhsp * 32 + tid] = s;
    }
}

// ---------------------------------------------------------------------------
// K6: fold context into Wout:  Wmod_b[c][h*32+d] =
//     (sum_e Wout[c][h*32+e] * ctx_sum[h][d][e]) / se_sum[h,d] * 1/(N*sqrt(32))
// block per (cg, b): 32 c-rows; thread = (c=tid&31, g=tid>>5 -> 16 hd outputs)
// ---------------------------------------------------------------------------
__global__ __launch_bounds__(256)
void wmod_kernel(const float* __restrict__ Wout, const float* __restrict__ ctxu,
                 const float* __restrict__ separt, bf16* __restrict__ wmod) {
    __shared__ float cs[4096];    // [h][d][e]
    __shared__ float ses[128];    // [h][d]
    int cg = blockIdx.x, b = blockIdx.y;
    int tid = threadIdx.x;
    for (int idx = tid; idx < 4096; idx += 256) {
        int hh = idx >> 10, rest = idx & 1023;
        float s = 0.f;
        #pragma unroll
        for (int sp = 0; sp < 4; ++sp)
            s += ctxu[(((size_t)(b * HEADS + hh) * 4) + sp) * 1024 + rest];
        cs[idx] = s;
    }
    if (tid < 128) {
        int hh = tid >> 5, d = tid & 31;
        float s = 0.f;
        #pragma unroll
        for (int sp = 0; sp < 4; ++sp)
            s += separt[(((size_t)(b * HEADS + hh) * 4) + sp) * 32 + d];
        ses[tid] = s;
    }
    __syncthreads();
    int c = cg * 32 + (tid & 31);
    int g = tid >> 5;               // 0..7
    int h = g >> 1, d0 = (g & 1) * 16;
    const float* wr = Wout + (size_t)c * INNER + h * DH;
    float w[32];
    #pragma unroll
    for (int i = 0; i < 8; ++i) {
        float4 t = *(const float4*)&wr[i * 4];
        w[i * 4] = t.x; w[i * 4 + 1] = t.y; w[i * 4 + 2] = t.z; w[i * 4 + 3] = t.w;
    }
    const float SCALE = 4.3158341e-05f;   // 1/(4096*sqrt(32))
    #pragma unroll
    for (int dd = 0; dd < 16; ++dd) {
        int d = d0 + dd;
        const float* cr = &cs[h * 1024 + d * 32];
        float s = 0.f;
        #pragma unroll
        for (int e4 = 0; e4 < 8; ++e4) {
            f32x4 t = *(const f32x4*)&cr[e4 * 4];
            s += w[e4 * 4] * t[0] + w[e4 * 4 + 1] * t[1]
               + w[e4 * 4 + 2] * t[2] + w[e4 * 4 + 3] * t[3];
        }
        float val = s * SCALE / ses[h * 32 + d];
        wmod[((size_t)b * CH + c) * INNER + h * DH + d] = f2b(val);
    }
}

// ---------------------------------------------------------------------------
// K8: final LN over channels + residual: out[b][c][n] = LN_c(y)[c][n] + x[c][n]
// y lives in qkv_t cols [128,384). block per (32-n tile, b); LDS 32x257 f32
// ---------------------------------------------------------------------------
__global__ __launch_bounds__(256)
void final_ln_kernel(const bf16* __restrict__ qkvt, const float* __restrict__ x,
                     float* __restrict__ out) {
    __shared__ float ys[32][257];
    __shared__ float red_s[8][32], red_q[8][32];
    __shared__ float mu_s[32], rs_s[32];
    int b = blockIdx.y, n0 = blockIdx.x * 32;
    int tid = threadIdx.x;
    const bf16* yb = qkvt + ((size_t)b * NPOS + n0) * QKV_ROWS + 128;
    for (int idx = tid; idx < 32 * 256; idx += 256) {
        int n = idx >> 8, c = idx & 255;
        ys[n][c] = b2f(yb[(size_t)n * QKV_ROWS + c]);
    }
    __syncthreads();
    {
        int n = tid & 31, q = tid >> 5;
        float s = 0.f, sq = 0.f;
        #pragma unroll
        for (int i = 0; i < 32; ++i) { float v = ys[n][q * 32 + i]; s += v; sq += v * v; }
        red_s[q][n] = s; red_q[q][n] = sq;
    }
    __syncthreads();
    if (tid < 32) {
        float s = 0.f, sq = 0.f;
        #pragma unroll
        for (int q = 0; q < 8; ++q) { s += red_s[q][tid]; sq += red_q[q][tid]; }
        float m = s * (1.f / 256.f);
        float var = sq * (1.f / 256.f) - m * m;
        mu_s[tid] = m; rs_s[tid] = rsqrtf(var + 1e-5f);
    }
    __syncthreads();
    const float* xb = x + (size_t)b * CH * NPOS;
    float* ob = out + (size_t)b * CH * NPOS;
    for (int idx = tid; idx < 32 * 256; idx += 256) {
        int c = idx >> 5, n = idx & 31;
        size_t gi = (size_t)c * NPOS + n0 + n;
        ob[gi] = (ys[n][c] - mu_s[n]) * rs_s[n] + xb[gi];
    }
}

// ---------------------------------------------------------------------------
extern "C" void kernel_launch(void* const* d_in, const int* in_sizes, int n_in,
                              void* d_out, int out_size, void* d_ws, size_t ws_size,
                              hipStream_t stream) {
    const float* x    = (const float*)d_in[0];   // [16,256,64,64]
    const float* Wqkv = (const float*)d_in[1];   // [384,256]
    const float* Wout = (const float*)d_in[2];   // [256,128]
    const float* bout = (const float*)d_in[3];   // [256]
    float* out = (float*)d_out;

    // workspace (67.3 MB total; round 2 proved >= 67.9 MB available):
    //  [0, 16.8M)        xnt: 8 batches of [n][256] bf16 (double-pumped)
    //                    later overlaid by ctxu / separt / wmod
    //  [16.8M, 67.1M)    qkv_t: [16][4096][384] bf16; after attn: cols[0,128)=p,
    //                    cols [128,384) overwritten by y
    //  [67.1M, 67.3M)    wq: Wqkv bf16
    char* ws = (char*)d_ws;
    bf16* xnt    = (bf16*)ws;
    bf16* qkvt   = (bf16*)(ws + 16777216);
    bf16* wq     = (bf16*)(ws + 67108864);
    float* ctxu  = (float*)ws;                    // 1,048,576 B
    float* separt= (float*)(ws + 1048576);        // 32,768 B
    bf16* wmod   = (bf16*)(ws + 1081344);         // 1,048,576 B

    convert_wq_kernel<<<384, 256, 0, stream>>>(Wqkv, wq);

    // LN+transpose and qkv GEMM, two batch-halves (xnt buffer reuse)
    for (int half = 0; half < 2; ++half) {
        const float* xh = x + (size_t)half * 8 * CH * NPOS;
        bf16* ch = qkvt + (size_t)half * 8 * NPOS * QKV_ROWS;
        norm_transpose_kernel<<<dim3(128, 8), 256, 0, stream>>>(xh, xnt);
        mfma_gemm_kernel<<<dim3(3, 32, 8), 256, 0, stream>>>(
            xnt, wq, ch, 256, 256, QKV_ROWS,
            (long)NPOS * CH, 0, (long)NPOS * QKV_ROWS, nullptr);
    }

    p_softmax_kernel<<<1024, 256, 0, stream>>>(qkvt);
    context_kernel<<<dim3(4, HEADS, BATCH), 256, 0, stream>>>(qkvt, ctxu, separt);
    wmod_kernel<<<dim3(8, BATCH), 256, 0, stream>>>(Wout, ctxu, separt, wmod);

    // y = P @ Wmod_b^T + bout, written into qkv_t cols [128,384)
    mfma_gemm_kernel<<<dim3(2, 32, BATCH), 256, 0, stream>>>(
        qkvt, wmod, qkvt + 128, 128, QKV_ROWS, QKV_ROWS,
        (long)NPOS * QKV_ROWS, (long)CH * INNER, (long)NPOS * QKV_ROWS, bout);

    final_ln_kernel<<<dim3(128, BATCH), 256, 0, stream>>>(qkvt, x, out);
}

// Round 4
// 225.028 us; speedup vs baseline: 2.7321x; 1.0951x over previous
//
#include <hip/hip_runtime.h>
#include <hip/hip_bf16.h>
#include <math.h>

// AttnBlock: B=16, C=256, H=W=64, heads=4, dim_head=32
#define BATCH 16
#define CH 256
#define NPOS 4096
#define INNER 128
#define HEADS 4
#define DH 32

typedef __hip_bfloat16 bf16;
typedef short bf8v __attribute__((ext_vector_type(8)));    // 8 bf16 (4 VGPRs)
typedef float f32x4 __attribute__((ext_vector_type(4)));

__device__ __forceinline__ float b2f(bf16 v) { return __bfloat162float(v); }
__device__ __forceinline__ float us2f(unsigned short u) {
    unsigned w = ((unsigned)u) << 16; float f; __builtin_memcpy(&f, &w, 4); return f;
}
__device__ __forceinline__ unsigned short f2us(float f) {
    bf16 h = __float2bfloat16(f); unsigned short u; __builtin_memcpy(&u, &h, 2); return u;
}
__device__ __forceinline__ bf16 f2b(float v) { return __float2bfloat16(v); }

// ---------------------------------------------------------------------------
// K1: fused LN + qkv GEMM + q-softmax.
// grid (32 n-tiles, 16 b), 256 threads. A-tile = LN(x)^T [128 n][256 c] bf16,
// fully LDS-resident (pad to 264 -> 528B rows, 16B aligned, ~2-way frag reads).
// Phases: k (Wqkv rows 128-255) -> kvt[...][0:128), v (256-383) -> kvt[128:256),
// q (0-127, last so A is dead) -> softmax -> p. Wqkv streamed fp32->bf16.
// ---------------------------------------------------------------------------
__global__ __launch_bounds__(256)
void fused_qkv_kernel(const float* __restrict__ x, const float* __restrict__ Wqkv,
                      bf16* __restrict__ p, bf16* __restrict__ kvt) {
    __shared__ bf16 A[128 * 264];      // 67584 B
    __shared__ bf16 Bb[128 * 32];      // 8192 B: B chunk / kv dump tile
    __shared__ float stats[512];       // 2048 B: LN partials -> mu/rs -> rdenom

    const int b = blockIdx.y, n0 = blockIdx.x * 128;
    const int tid = threadIdx.x;
    const int wave = tid >> 6, lane = tid & 63;
    const int wm = (wave >> 1) * 64, wn = (wave & 1) * 64;
    const int lrow = lane & 15, kq = lane >> 4;

    // ---- stage x tile (raw bf16) + per-thread LN partial stats ----
    {
        const int n = tid & 127, chalf = tid >> 7;
        const float* xp = x + ((size_t)b * CH + chalf * 128) * NPOS + n0 + n;
        float s = 0.f, sq = 0.f;
        for (int i0 = 0; i0 < 128; i0 += 8) {
            bf8v bv;
            #pragma unroll
            for (int j = 0; j < 8; ++j) {
                float v = xp[(size_t)(i0 + j) * NPOS];
                s += v; sq += v * v;
                bv[j] = (short)f2us(v);
            }
            *(bf8v*)&A[n * 264 + chalf * 128 + i0] = bv;
        }
        stats[tid * 2] = s; stats[tid * 2 + 1] = sq;
    }
    __syncthreads();
    if (tid < 128) {
        float s  = stats[tid * 2] + stats[(tid + 128) * 2];
        float sq = stats[tid * 2 + 1] + stats[(tid + 128) * 2 + 1];
        float m = s * (1.f / 256.f);
        float var = sq * (1.f / 256.f) - m * m;
        stats[tid * 2] = m;
        stats[tid * 2 + 1] = rsqrtf(var + 1e-5f);
    }
    __syncthreads();
    // ---- normalize A in place (u32 pairs, c-fast, conflict-free) ----
    {
        unsigned* A32 = (unsigned*)A;
        #pragma unroll 4
        for (int i = 0; i < 64; ++i) {
            int idx = i * 256 + tid;
            int c2 = idx & 127, n = idx >> 7;
            unsigned u = A32[n * 132 + c2];
            float m = stats[n * 2], rs = stats[n * 2 + 1];
            float v0 = (us2f((unsigned short)(u & 0xffffu)) - m) * rs;
            float v1 = (us2f((unsigned short)(u >> 16)) - m) * rs;
            A32[n * 132 + c2] = (unsigned)f2us(v0) | ((unsigned)f2us(v1) << 16);
        }
    }

    for (int ph = 0; ph < 3; ++ph) {
        const int colbase = (ph == 2) ? 0 : (ph + 1) * 128;   // k, v, q
        f32x4 acc[4][4];
        #pragma unroll
        for (int i = 0; i < 4; ++i)
            #pragma unroll
            for (int j = 0; j < 4; ++j) acc[i][j] = (f32x4){0.f, 0.f, 0.f, 0.f};

        for (int k0 = 0; k0 < 256; k0 += 32) {
            __syncthreads();   // protect Bb from previous use
            // stage B chunk: 128 cols x 32 k, fp32 -> bf16
            #pragma unroll
            for (int i = 0; i < 4; ++i) {
                int s = i * 256 + tid;           // 1024 float4 chunks
                int col = s >> 3, q4 = s & 7;
                float4 w = *(const float4*)&Wqkv[(size_t)(colbase + col) * 256 + k0 + q4 * 4];
                ushort4 wb;
                wb.x = f2us(w.x); wb.y = f2us(w.y); wb.z = f2us(w.z); wb.w = f2us(w.w);
                *(ushort4*)&Bb[col * 32 + q4 * 4] = wb;
            }
            __syncthreads();
            bf8v af[4], bfr[4];
            #pragma unroll
            for (int t = 0; t < 4; ++t)
                af[t] = *(const bf8v*)&A[(wm + t * 16 + lrow) * 264 + k0 + kq * 8];
            #pragma unroll
            for (int t = 0; t < 4; ++t)
                bfr[t] = *(const bf8v*)&Bb[(wn + t * 16 + lrow) * 32 + kq * 8];
            #pragma unroll
            for (int mt = 0; mt < 4; ++mt)
                #pragma unroll
                for (int nt = 0; nt < 4; ++nt)
                    acc[mt][nt] = __builtin_amdgcn_mfma_f32_16x16x32_bf16(
                        af[mt], bfr[nt], acc[mt][nt], 0, 0, 0);
        }

        if (ph < 2) {
            // k/v epilogue: 4 row-passes of 32 via Bb for coalesced stores
            unsigned* B32 = (unsigned*)Bb;
            unsigned* kv32 = (unsigned*)kvt;
            for (int pr = 0; pr < 4; ++pr) {
                __syncthreads();
                if ((wave >> 1) == (pr >> 1)) {
                    int mtb = (pr & 1) * 2;
                    #pragma unroll
                    for (int mi = 0; mi < 2; ++mi) {
                        int mt = mtb + mi;
                        #pragma unroll
                        for (int nt = 0; nt < 4; ++nt)
                            #pragma unroll
                            for (int r = 0; r < 4; ++r) {
                                int rl = mi * 16 + kq * 4 + r;       // 0..31
                                Bb[rl * 128 + wn + nt * 16 + lrow] = f2b(acc[mt][nt][r]);
                            }
                    }
                }
                __syncthreads();
                #pragma unroll
                for (int i = 0; i < 8; ++i) {
                    int idx = i * 256 + tid;     // 2048 u32
                    int c2 = idx & 63, rl = idx >> 6;
                    kv32[(size_t)(b * NPOS + n0 + pr * 32 + rl) * 128 + ph * 64 + c2] =
                        B32[rl * 64 + c2];
                }
            }
        } else {
            // q epilogue: dump raw accs over A, softmax per (row, head), store p
            __syncthreads();
            bf16* pt = A;                        // [128][132]
            #pragma unroll
            for (int mt = 0; mt < 4; ++mt)
                #pragma unroll
                for (int nt = 0; nt < 4; ++nt)
                    #pragma unroll
                    for (int r = 0; r < 4; ++r)
                        pt[(wm + mt * 16 + kq * 4 + r) * 132 + wn + nt * 16 + lrow] =
                            f2b(acc[mt][nt][r]);
            __syncthreads();
            {   // reciprocal softmax denominators (no max-sub: |q| < ~6 -> safe)
                int row = tid >> 1, hp = (tid & 1) * 2;
                float s0 = 0.f, s1 = 0.f;
                #pragma unroll 8
                for (int j = 0; j < 32; ++j) s0 += __expf(b2f(pt[row * 132 + hp * 32 + j]));
                #pragma unroll 8
                for (int j = 0; j < 32; ++j) s1 += __expf(b2f(pt[row * 132 + hp * 32 + 32 + j]));
                stats[row * 4 + hp] = 1.f / s0;
                stats[row * 4 + hp + 1] = 1.f / s1;
            }
            __syncthreads();
            unsigned* pt32 = (unsigned*)pt;
            unsigned* pg32 = (unsigned*)p;
            #pragma unroll 4
            for (int i = 0; i < 32; ++i) {
                int idx = i * 256 + tid;         // 8192 u32
                int c2 = idx & 63, n = idx >> 6;
                unsigned u = pt32[n * 66 + c2];
                float rd = stats[n * 4 + (c2 >> 4)];
                float v0 = __expf(us2f((unsigned short)(u & 0xffffu))) * rd;
                float v1 = __expf(us2f((unsigned short)(u >> 16))) * rd;
                pg32[(size_t)(b * NPOS + n0 + n) * 64 + c2] =
                    (unsigned)f2us(v0) | ((unsigned)f2us(v1) << 16);
            }
        }
    }
}

// ---------------------------------------------------------------------------
// K2: unnormalized context + sumexp partials (dense kvt [b][n][256] input).
// ctxu[(bh,sp)][d][e] = sum_n exp(k[n,d]) * v[n,e]; separt = sum exp.
// ---------------------------------------------------------------------------
__global__ __launch_bounds__(256)
void context_kernel(const bf16* __restrict__ kvt, float* __restrict__ ctxu,
                    float* __restrict__ separt) {
    __shared__ float ks[128][36];
    __shared__ float vs[128][36];
    __shared__ float red_se[4][32];
    int sp = blockIdx.x, h = blockIdx.y, b = blockIdx.z;
    int tid = threadIdx.x;
    int wave = tid >> 6, lane = tid & 63;
    int eg = lane & 7, dg = lane >> 3;
    int sd = tid & 31, sq = (tid >> 5) & 3;
    const int koff = h * DH, voff = 128 + h * DH;
    size_t rowbase = ((size_t)b * NPOS + sp * 1024) * 256;

    float acc[4][4] = {};
    float se_loc = 0.f;

    for (int nc = 0; nc < 1024; nc += 128) {
        for (int t = tid; t < 1024; t += 256) {
            int n = t >> 3, dq = t & 7;
            const bf16* row = kvt + rowbase + (size_t)(nc + n) * 256;
            ushort4 ku = *(const ushort4*)(row + koff + dq * 4);
            ushort4 vu = *(const ushort4*)(row + voff + dq * 4);
            f32x4 kf, vf;
            kf[0] = __expf(us2f(ku.x)); kf[1] = __expf(us2f(ku.y));
            kf[2] = __expf(us2f(ku.z)); kf[3] = __expf(us2f(ku.w));
            vf[0] = us2f(vu.x); vf[1] = us2f(vu.y); vf[2] = us2f(vu.z); vf[3] = us2f(vu.w);
            *(f32x4*)&ks[n][dq * 4] = kf;
            *(f32x4*)&vs[n][dq * 4] = vf;
        }
        __syncthreads();
        #pragma unroll 4
        for (int i = 0; i < 32; ++i) {
            int n = wave * 32 + i;
            f32x4 kv = *(const f32x4*)&ks[n][dg * 4];
            f32x4 vv = *(const f32x4*)&vs[n][eg * 4];
            #pragma unroll
            for (int j = 0; j < 4; ++j)
                #pragma unroll
                for (int i2 = 0; i2 < 4; ++i2)
                    acc[j][i2] += kv[j] * vv[i2];
        }
        if (tid < 128) {
            float s = 0.f;
            #pragma unroll 8
            for (int i = 0; i < 32; ++i) s += ks[sq * 32 + i][sd];
            se_loc += s;
        }
        __syncthreads();
    }

    if (tid < 128) red_se[sq][sd] = se_loc;
    float* red = &ks[0][0];   // 4608 floats >= 4096
    #pragma unroll
    for (int j = 0; j < 4; ++j)
        #pragma unroll
        for (int i = 0; i < 4; ++i)
            red[(wave * 64 + lane) * 16 + j * 4 + i] = acc[j][i];
    __syncthreads();
    size_t bhsp = ((size_t)(b * HEADS + h) * 4 + sp);
    for (int idx = tid; idx < 1024; idx += 256) {
        int d = idx >> 5, e = idx & 31;
        int l = (d >> 2) * 8 + (e >> 2);
        int slot = (d & 3) * 4 + (e & 3);
        float s = 0.f;
        #pragma unroll
        for (int w = 0; w < 4; ++w) s += red[(w * 64 + l) * 16 + slot];
        ctxu[bhsp * 1024 + idx] = s;
    }
    if (tid < 32) {
        float s = red_se[0][tid] + red_se[1][tid] + red_se[2][tid] + red_se[3][tid];
        separt[bhsp * 32 + tid] = s;
    }
}

// ---------------------------------------------------------------------------
// K3: wmod_b[c][h*32+d] = (sum_e Wout[c][h*32+e]*ctx[h][d][e]) / se[h,d] / (N*sqrt32)
// ---------------------------------------------------------------------------
__global__ __launch_bounds__(256)
void wmod_kernel(const float* __restrict__ Wout, const float* __restrict__ ctxu,
                 const float* __restrict__ separt, bf16* __restrict__ wmod) {
    __shared__ float cs[4096];
    __shared__ float ses[128];
    int cg = blockIdx.x, b = blockIdx.y;
    int tid = threadIdx.x;
    for (int idx = tid; idx < 4096; idx += 256) {
        int hh = idx >> 10, rest = idx & 1023;
        float s = 0.f;
        #pragma unroll
        for (int sp = 0; sp < 4; ++sp)
            s += ctxu[(((size_t)(b * HEADS + hh) * 4) + sp) * 1024 + rest];
        cs[idx] = s;
    }
    if (tid < 128) {
        int hh = tid >> 5, d = tid & 31;
        float s = 0.f;
        #pragma unroll
        for (int sp = 0; sp < 4; ++sp)
            s += separt[(((size_t)(b * HEADS + hh) * 4) + sp) * 32 + d];
        ses[tid] = s;
    }
    __syncthreads();
    int c = cg * 32 + (tid & 31);
    int g = tid >> 5;
    int h = g >> 1, d0 = (g & 1) * 16;
    const float* wr = Wout + (size_t)c * INNER + h * DH;
    float w[32];
    #pragma unroll
    for (int i = 0; i < 8; ++i) {
        float4 t = *(const float4*)&wr[i * 4];
        w[i * 4] = t.x; w[i * 4 + 1] = t.y; w[i * 4 + 2] = t.z; w[i * 4 + 3] = t.w;
    }
    const float SCALE = 4.3158341e-05f;   // 1/(4096*sqrt(32))
    #pragma unroll
    for (int dd = 0; dd < 16; ++dd) {
        int d = d0 + dd;
        const float* cr = &cs[h * 1024 + d * 32];
        float s = 0.f;
        #pragma unroll
        for (int e4 = 0; e4 < 8; ++e4) {
            f32x4 t = *(const f32x4*)&cr[e4 * 4];
            s += w[e4 * 4] * t[0] + w[e4 * 4 + 1] * t[1]
               + w[e4 * 4 + 2] * t[2] + w[e4 * 4 + 3] * t[3];
        }
        float val = s * SCALE / ses[h * 32 + d];
        wmod[((size_t)b * CH + c) * INNER + h * DH + d] = f2b(val);
    }
}

// ---------------------------------------------------------------------------
// K4: fused y-GEMM (y[n][c] = sum_hd p[n][hd]*wmod[c][hd] + bout[c]) + channel
// LN + residual -> out fp32. grid (32 n-tiles, 16 b). One block = 128n x 256c.
// ---------------------------------------------------------------------------
__global__ __launch_bounds__(256)
void fused_out_kernel(const bf16* __restrict__ p, const bf16* __restrict__ wmod,
                      const float* __restrict__ bout, const float* __restrict__ x,
                      float* __restrict__ out) {
    __shared__ char lds[51200];
    bf16* Ap = (bf16*)lds;                 // [128][136] = 34816 B (union: ct)
    bf16* Bw = (bf16*)(lds + 34816);       // [256][32]  = 16384 B (union: st)
    float* ct = (float*)lds;               // [256][33] f32 = 33792 B
    float* st = (float*)(lds + 34816);     // stats: [2][128][2] + musr[128][2]

    const int b = blockIdx.y, n0 = blockIdx.x * 128;
    const int tid = threadIdx.x;
    const int wave = tid >> 6, lane = tid & 63;
    const int wm = (wave >> 1) * 64, wn2 = (wave & 1) * 128;
    const int lrow = lane & 15, kq = lane >> 4;

    // stage Ap = p tile [128][128]
    {
        const unsigned* pg32 = (const unsigned*)p;
        unsigned* A32 = (unsigned*)Ap;
        #pragma unroll 4
        for (int i = 0; i < 32; ++i) {
            int idx = i * 256 + tid;
            int c2 = idx & 63, n = idx >> 6;
            A32[n * 68 + c2] = pg32[(size_t)(b * NPOS + n0 + n) * 64 + c2];
        }
    }

    f32x4 acc[4][8];
    #pragma unroll
    for (int i = 0; i < 4; ++i)
        #pragma unroll
        for (int j = 0; j < 8; ++j) acc[i][j] = (f32x4){0.f, 0.f, 0.f, 0.f};

    const bf16* wb = wmod + (size_t)b * CH * INNER;
    for (int k0 = 0; k0 < 128; k0 += 32) {
        __syncthreads();
        #pragma unroll
        for (int i = 0; i < 4; ++i) {
            int s = i * 256 + tid;             // 1024 16B chunks
            int col = s >> 2, q4 = s & 3;
            uint4 u = *(const uint4*)&wb[(size_t)col * 128 + k0 + q4 * 8];
            *(uint4*)&Bw[col * 32 + q4 * 8] = u;
        }
        __syncthreads();
        bf8v af[4], bfr[8];
        #pragma unroll
        for (int t = 0; t < 4; ++t)
            af[t] = *(const bf8v*)&Ap[(wm + t * 16 + lrow) * 136 + k0 + kq * 8];
        #pragma unroll
        for (int t = 0; t < 8; ++t)
            bfr[t] = *(const bf8v*)&Bw[(wn2 + t * 16 + lrow) * 32 + kq * 8];
        #pragma unroll
        for (int mt = 0; mt < 4; ++mt)
            #pragma unroll
            for (int nt = 0; nt < 8; ++nt)
                acc[mt][nt] = __builtin_amdgcn_mfma_f32_16x16x32_bf16(
                    af[mt], bfr[nt], acc[mt][nt], 0, 0, 0);
    }

    // bias add (before LN, matches reference)
    #pragma unroll
    for (int nt = 0; nt < 8; ++nt) {
        float bv = bout[wn2 + nt * 16 + lrow];
        #pragma unroll
        for (int mt = 0; mt < 4; ++mt)
            #pragma unroll
            for (int r = 0; r < 4; ++r) acc[mt][nt][r] += bv;
    }

    __syncthreads();   // Bw frag reads done; st region reusable
    // LN stats: per (mt,r) row, sum over this wave's 128 cols via shfl_xor on lrow
    #pragma unroll
    for (int mt = 0; mt < 4; ++mt)
        #pragma unroll
        for (int r = 0; r < 4; ++r) {
            float s = 0.f, sq = 0.f;
            #pragma unroll
            for (int nt = 0; nt < 8; ++nt) {
                float v = acc[mt][nt][r];
                s += v; sq += v * v;
            }
            #pragma unroll
            for (int m = 1; m <= 8; m <<= 1) {
                s += __shfl_xor(s, m, 64);
                sq += __shfl_xor(sq, m, 64);
            }
            if (lrow == 0) {
                int row = wm + mt * 16 + kq * 4 + r;
                st[(wave & 1) * 256 + row * 2] = s;
                st[(wave & 1) * 256 + row * 2 + 1] = sq;
            }
        }
    __syncthreads();
    if (tid < 128) {
        float s  = st[tid * 2] + st[256 + tid * 2];
        float sq = st[tid * 2 + 1] + st[256 + tid * 2 + 1];
        float m = s * (1.f / 256.f);
        float var = sq * (1.f / 256.f) - m * m;
        st[512 + tid * 2] = m;
        st[512 + tid * 2 + 1] = rsqrtf(var + 1e-5f);
    }
    __syncthreads();
    // normalize accs in place
    #pragma unroll
    for (int mt = 0; mt < 4; ++mt)
        #pragma unroll
        for (int r = 0; r < 4; ++r) {
            int row = wm + mt * 16 + kq * 4 + r;
            float m = st[512 + row * 2], rs = st[512 + row * 2 + 1];
            #pragma unroll
            for (int nt = 0; nt < 8; ++nt)
                acc[mt][nt][r] = (acc[mt][nt][r] - m) * rs;
        }

    // 4 output chunks of 32 rows: LDS transpose -> coalesced fp32 store + residual
    for (int pr = 0; pr < 4; ++pr) {
        __syncthreads();
        if ((wave >> 1) == (pr >> 1)) {
            int mtb = (pr & 1) * 2;
            #pragma unroll
            for (int mi = 0; mi < 2; ++mi) {
                int mt = mtb + mi;
                #pragma unroll
                for (int nt = 0; nt < 8; ++nt)
                    #pragma unroll
                    for (int r = 0; r < 4; ++r) {
                        int rl = mi * 16 + kq * 4 + r;
                        ct[(wn2 + nt * 16 + lrow) * 33 + rl] = acc[mt][nt][r];
                    }
            }
        }
        __syncthreads();
        #pragma unroll 4
        for (int i = 0; i < 32; ++i) {
            int idx = i * 256 + tid;       // 8192 f32
            int n = idx & 31, c = idx >> 5;
            size_t gi = ((size_t)b * CH + c) * NPOS + n0 + pr * 32 + n;
            out[gi] = ct[c * 33 + n] + x[gi];
        }
    }
}

// ---------------------------------------------------------------------------
extern "C" void kernel_launch(void* const* d_in, const int* in_sizes, int n_in,
                              void* d_out, int out_size, void* d_ws, size_t ws_size,
                              hipStream_t stream) {
    const float* x    = (const float*)d_in[0];   // [16,256,64,64]
    const float* Wqkv = (const float*)d_in[1];   // [384,256]
    const float* Wout = (const float*)d_in[2];   // [256,128]
    const float* bout = (const float*)d_in[3];   // [256]
    float* out = (float*)d_out;

    // workspace (~52.5 MB)
    char* ws = (char*)d_ws;
    bf16*  p      = (bf16*)ws;                       // 16*4096*128*2 = 16777216
    bf16*  kvt    = (bf16*)(ws + 16777216);          // 16*4096*256*2 = 33554432
    float* ctxu   = (float*)(ws + 50331648);         // 16*4*4*1024*4 = 1048576
    float* separt = (float*)(ws + 51380224);         // 32768
    bf16*  wmod   = (bf16*)(ws + 51412992);          // 16*256*128*2 = 1048576

    fused_qkv_kernel<<<dim3(32, BATCH), 256, 0, stream>>>(x, Wqkv, p, kvt);
    context_kernel<<<dim3(4, HEADS, BATCH), 256, 0, stream>>>(kvt, ctxu, separt);
    wmod_kernel<<<dim3(8, BATCH), 256, 0, stream>>>(Wout, ctxu, separt, wmod);
    fused_out_kernel<<<dim3(32, BATCH), 256, 0, stream>>>(p, wmod, bout, x, out);
}